// Round 7
// baseline (383.041 us; speedup 1.0000x reference)
//
#include <hip/hip_runtime.h>

#define LOG2E 1.4426950408889634f
#define NB 4
#define NL 256
#define ND 256
#define NH 256

typedef __attribute__((ext_vector_type(8))) short s16x8;
typedef __attribute__((ext_vector_type(4))) short s16x4;
typedef __attribute__((ext_vector_type(4))) float f32x4;

static __device__ __forceinline__ float b2f(unsigned short u) {
  return __builtin_bit_cast(float, (unsigned int)u << 16);
}
static __device__ __forceinline__ unsigned short f2b(float f) {
  unsigned int x = __builtin_bit_cast(unsigned int, f);
  return (unsigned short)((x + 0x7fffu + ((x >> 16) & 1u)) >> 16);
}
static __device__ __forceinline__ float ftanh(float x) {
  float e = __builtin_amdgcn_exp2f(x * 2.8853900817779268f);
  return 1.0f - 2.0f * __builtin_amdgcn_rcpf(e + 1.0f);
}

// ws layout (2 MB): X fp32 [0,1M) ; C1 bf16 [1M,1.5M) ; M1 bf16 [1.5M,2M)

__global__ void __launch_bounds__(256) prep(const float* __restrict__ Hq,
                                            const float* __restrict__ Wc1,
                                            const float* __restrict__ Wm,
                                            const float* __restrict__ Wb,
                                            float* __restrict__ ws) {
  __shared__ __align__(16) float a_s[4][256];
  const int m0 = blockIdx.x * 4;
  const int which = blockIdx.y;  // 0=C1, 1=M1, 2=X
  const float* W = (which == 0) ? Wc1 : (which == 1) ? Wm : Wb;
  const int tid = threadIdx.x;
  #pragma unroll
  for (int j = 0; j < 4; ++j)
    a_s[j][tid] = Hq[(m0 + j) * ND + tid];
  __syncthreads();
  float acc[4] = {0.f, 0.f, 0.f, 0.f};
  for (int k = 0; k < 256; ++k) {
    const float w = W[k * NH + tid];
    acc[0] += a_s[0][k] * w;
    acc[1] += a_s[1][k] * w;
    acc[2] += a_s[2][k] * w;
    acc[3] += a_s[3][k] * w;
  }
  if (which == 2) {
    #pragma unroll
    for (int j = 0; j < 4; ++j) ws[(m0 + j) * NH + tid] = acc[j];
  } else {
    unsigned short* O = (unsigned short*)((char*)ws + 1048576 + which * 524288);
    #pragma unroll
    for (int j = 0; j < 4; ++j) O[(m0 + j) * NH + tid] = f2b(acc[j]);
  }
}

__global__ void __launch_bounds__(256) fused_multiway(
    const float* __restrict__ Hp, const float* __restrict__ Hq,
    const float* __restrict__ Wc2, const float* __restrict__ Wm,
    const float* __restrict__ Wd, const float* __restrict__ vc,
    const float* __restrict__ vd, const float* __restrict__ vm,
    const float* __restrict__ ws, float* __restrict__ out)
{
  const int p = blockIdx.x, b = blockIdx.y;
  const int tid = threadIdx.x;
  const int wave = tid >> 6, lane = tid & 63;
  const int quad = lane >> 4, c16 = lane & 15;

  __shared__ __align__(16) short As[256 * 40];
  __shared__ __align__(16) short Bs[64 * 40];
  __shared__ __align__(16) float sc4[4 * 256];
  __shared__ __align__(16) float hp_s[256];
  __shared__ __align__(16) float c2_s[256];
  __shared__ __align__(16) float m2_s[256];
  __shared__ __align__(16) float vc_s[256];
  __shared__ __align__(16) float vd_s[256];
  __shared__ __align__(16) float vm_s[256];
  __shared__ __align__(16) float invsum[4];

  const float* X = ws;
  const unsigned short* C1 = (const unsigned short*)((const char*)ws + 1048576);
  const unsigned short* M1 = (const unsigned short*)((const char*)ws + 1572864);

  {
    hp_s[tid] = Hp[(b * NL + p) * ND + tid];
    vc_s[tid] = vc[tid];
    vd_s[tid] = vd[tid];
    vm_s[tid] = vm[tid];
  }
  __syncthreads();

  { // GEMV: c2 = Wc2^T hp, m2 = Wm^T hp
    float aC = 0.f, aM = 0.f;
    for (int k = 0; k < 256; ++k) {
      const float hk = hp_s[k];
      aC += hk * Wc2[k * NH + tid];
      aM += hk * Wm[k * NH + tid];
    }
    c2_s[tid] = aC;
    m2_s[tid] = aM;
  }
  __syncthreads();

  { // scores c, b, m
    const int qsub = lane >> 4;
    const int hb = c16 * 4;
    for (int qg = 0; qg < 16; ++qg) {
      const int q = wave * 64 + qg * 4 + qsub;
      const unsigned short* c1r = C1 + (b * NL + q) * NH;
      const unsigned short* m1r = M1 + (b * NL + q) * NH;
      const float* xr = X + (b * NL + q) * ND;
      float pc = 0.f, pm = 0.f, pb = 0.f;
      #pragma unroll
      for (int hi = 0; hi < 4; ++hi) {
        const int h = hb + hi * 64;
        s16x4 c1v = *(const s16x4*)(c1r + h);
        s16x4 m1v = *(const s16x4*)(m1r + h);
        f32x4 xv  = *(const f32x4*)(xr + h);
        #pragma unroll
        for (int i = 0; i < 4; ++i) {
          pc += vc_s[h + i] * ftanh(b2f((unsigned short)c1v[i]) + c2_s[h + i]);
          pm += vm_s[h + i] * ftanh(b2f((unsigned short)m1v[i]) - m2_s[h + i]);
          pb += hp_s[h + i] * xv[i];
        }
      }
      #pragma unroll
      for (int m = 1; m < 16; m <<= 1) {
        pc += __shfl_xor(pc, m, 64);
        pm += __shfl_xor(pm, m, 64);
        pb += __shfl_xor(pb, m, 64);
      }
      if (c16 == 0) {
        sc4[q]       = pc;
        sc4[256 + q] = pb;
        sc4[768 + q] = pm;
      }
    }
  }

  { // branch d via MFMA 16x16x32 bf16
    const int wq0 = wave * 64;
    float sd_reg[4][4];
    #pragma unroll
    for (int mt = 0; mt < 4; ++mt)
      #pragma unroll
      for (int r = 0; r < 4; ++r) sd_reg[mt][r] = 0.f;

    for (int ht = 0; ht < 4; ++ht) {
      const int h0 = ht * 64;
      f32x4 acc[4][4];
      #pragma unroll
      for (int mt = 0; mt < 4; ++mt)
        #pragma unroll
        for (int nt = 0; nt < 4; ++nt) acc[mt][nt] = f32x4{0.f, 0.f, 0.f, 0.f};

      for (int kt = 0; kt < 8; ++kt) {
        const int k0 = kt * 32;
        __syncthreads();
        {
          const int rw = tid >> 2, kc = (tid & 3) * 8;
          #pragma unroll
          for (int j = 0; j < 4; ++j) {
            const int q = rw + j * 64;
            const float* src = Hq + (b * NL + q) * ND + k0 + kc;
            f32x4 f0 = *(const f32x4*)(src);
            f32x4 f1 = *(const f32x4*)(src + 4);
            s16x8 av;
            #pragma unroll
            for (int i = 0; i < 4; ++i) av[i] = (short)f2b(f0[i]);
            #pragma unroll
            for (int i = 0; i < 4; ++i) av[4 + i] = (short)f2b(f1[i]);
            *(s16x8*)(As + q * 40 + kc) = av;
          }
        }
        {
          const int n = tid & 63, kc = (tid >> 6) * 8;
          s16x8 bv;
          #pragma unroll
          for (int i = 0; i < 8; ++i) {
            const int k = k0 + kc + i;
            bv[i] = (short)f2b(Wd[k * NH + h0 + n] * hp_s[k]);
          }
          *(s16x8*)(Bs + n * 40 + kc) = bv;
        }
        __syncthreads();
        s16x8 a8[4];
        #pragma unroll
        for (int mt = 0; mt < 4; ++mt)
          a8[mt] = *(const s16x8*)(As + (wq0 + mt * 16 + c16) * 40 + quad * 8);
        #pragma unroll
        for (int nt = 0; nt < 4; ++nt) {
          s16x8 b8 = *(const s16x8*)(Bs + (nt * 16 + c16) * 40 + quad * 8);
          #pragma unroll
          for (int mt = 0; mt < 4; ++mt)
            acc[mt][nt] = __builtin_amdgcn_mfma_f32_16x16x32_bf16(
                a8[mt], b8, acc[mt][nt], 0, 0, 0);
        }
      }
      #pragma unroll
      for (int mt = 0; mt < 4; ++mt) {
        float part[4] = {0.f, 0.f, 0.f, 0.f};
        #pragma unroll
        for (int nt = 0; nt < 4; ++nt) {
          const float vdh = vd_s[h0 + nt * 16 + c16];
          #pragma unroll
          for (int r = 0; r < 4; ++r)
            part[r] += vdh * ftanh(acc[mt][nt][r]);
        }
        #pragma unroll
        for (int r = 0; r < 4; ++r) {
          float v = part[r];
          #pragma unroll
          for (int m = 1; m < 16; m <<= 1) v += __shfl_xor(v, m, 64);
          sd_reg[mt][r] += v;
        }
      }
    }
    if (c16 == 0) {
      #pragma unroll
      for (int mt = 0; mt < 4; ++mt)
        #pragma unroll
        for (int r = 0; r < 4; ++r)
          sc4[512 + wq0 + mt * 16 + quad * 4 + r] = sd_reg[mt][r];
    }
  }

  __syncthreads();

  { // softmax; wave w owns branch w (0=c,1=b,2=d,3=m)
    float s0 = sc4[wave * 256 + lane];
    float s1 = sc4[wave * 256 + lane + 64];
    float s2 = sc4[wave * 256 + lane + 128];
    float s3 = sc4[wave * 256 + lane + 192];
    float mx = fmaxf(fmaxf(s0, s1), fmaxf(s2, s3));
    #pragma unroll
    for (int m = 1; m < 64; m <<= 1) mx = fmaxf(mx, __shfl_xor(mx, m, 64));
    float e0 = __builtin_amdgcn_exp2f((s0 - mx) * LOG2E);
    float e1 = __builtin_amdgcn_exp2f((s1 - mx) * LOG2E);
    float e2 = __builtin_amdgcn_exp2f((s2 - mx) * LOG2E);
    float e3 = __builtin_amdgcn_exp2f((s3 - mx) * LOG2E);
    float sm = e0 + e1 + e2 + e3;
    #pragma unroll
    for (int m = 1; m < 64; m <<= 1) sm += __shfl_xor(sm, m, 64);
    sc4[wave * 256 + lane]       = e0;
    sc4[wave * 256 + lane + 64]  = e1;
    sc4[wave * 256 + lane + 128] = e2;
    sc4[wave * 256 + lane + 192] = e3;
    if (lane == 0) invsum[wave] = __builtin_amdgcn_rcpf(sm);
  }
  __syncthreads();

  { // attend: wave w -> output region w, row (b,p); fp32 output
    float a0 = 0.f, a1 = 0.f, a2 = 0.f, a3 = 0.f;
    for (int q = 0; q < 256; ++q) {
      const float a = sc4[wave * 256 + q];
      f32x4 hv = *(const f32x4*)(Hq + (b * NL + q) * ND + lane * 4);
      a0 += a * hv.x; a1 += a * hv.y; a2 += a * hv.z; a3 += a * hv.w;
    }
    const float inv = invsum[wave];
    f32x4 ov;
    ov.x = a0 * inv;
    ov.y = a1 * inv;
    ov.z = a2 * inv;
    ov.w = a3 * inv;
    *(f32x4*)(out + ((wave * NB + b) * NL + p) * ND + lane * 4) = ov;
  }
}

extern "C" void kernel_launch(void* const* d_in, const int* in_sizes, int n_in,
                              void* d_out, int out_size, void* d_ws, size_t ws_size,
                              hipStream_t stream) {
  const float* Hp  = (const float*)d_in[0];
  const float* Hq  = (const float*)d_in[1];
  const float* Wc1 = (const float*)d_in[2];
  const float* Wc2 = (const float*)d_in[3];
  const float* vc  = (const float*)d_in[4];
  const float* Wb  = (const float*)d_in[5];
  const float* Wd  = (const float*)d_in[6];
  const float* vd  = (const float*)d_in[7];
  const float* Wm  = (const float*)d_in[8];
  const float* vm  = (const float*)d_in[9];
  float* ws = (float*)d_ws;
  float* out = (float*)d_out;

  hipLaunchKernelGGL(prep, dim3(256, 3), dim3(256), 0, stream,
                     Hq, Wc1, Wm, Wb, ws);
  hipLaunchKernelGGL(fused_multiway, dim3(256, 4), dim3(256), 0, stream,
                     Hp, Hq, Wc2, Wm, Wd, vc, vd, vm, ws, out);
}

// Round 8
// 344.489 us; speedup vs baseline: 1.1119x; 1.1119x over previous
//
#include <hip/hip_runtime.h>

#define LOG2E 1.4426950408889634f
#define NB 4
#define NL 256
#define ND 256
#define NH 256

typedef __attribute__((ext_vector_type(8))) short s16x8;
typedef __attribute__((ext_vector_type(4))) short s16x4;
typedef __attribute__((ext_vector_type(4))) float f32x4;

static __device__ __forceinline__ float b2f(unsigned short u) {
  return __builtin_bit_cast(float, (unsigned int)u << 16);
}
static __device__ __forceinline__ unsigned short f2b(float f) {
  unsigned int x = __builtin_bit_cast(unsigned int, f);
  return (unsigned short)((x + 0x7fffu + ((x >> 16) & 1u)) >> 16);
}
static __device__ __forceinline__ float ftanh(float x) {
  float e = __builtin_amdgcn_exp2f(x * 2.8853900817779268f);
  return 1.0f - 2.0f * __builtin_amdgcn_rcpf(e + 1.0f);
}

// ws layout (4.5 MB):
//   X    fp32 [0,       1M)   : Hq@Wb
//   C1   bf16 [1M,    1.5M)   : Hq@Wc1
//   M1   bf16 [1.5M,    2M)   : Hq@Wm
//   C2F  fp32 [2M,      3M)   : Hp@Wc2
//   M2F  fp32 [3M,      4M)   : Hp@Wm
//   Hqb  bf16 [4M,    4.5M)   : bf16(Hq)

__global__ void __launch_bounds__(256) prep(
    const float* __restrict__ Hq, const float* __restrict__ Hp,
    const float* __restrict__ Wc1, const float* __restrict__ Wc2,
    const float* __restrict__ Wb, const float* __restrict__ Wm,
    float* __restrict__ ws)
{
  const int m0 = blockIdx.x * 4;
  const int which = blockIdx.y;  // 0=C1 1=M1 2=X 3=C2F 4=M2F 5=Hqb
  const int tid = threadIdx.x;
  if (which == 5) {
    unsigned short* Hqb = (unsigned short*)((char*)ws + 4194304);
    #pragma unroll
    for (int j = 0; j < 4; ++j)
      Hqb[(m0 + j) * ND + tid] = f2b(Hq[(m0 + j) * ND + tid]);
    return;
  }
  __shared__ __align__(16) float a_s[4][256];
  const float* A = (which >= 3) ? Hp : Hq;
  const float* W = (which == 0) ? Wc1 : (which == 1) ? Wm :
                   (which == 2) ? Wb  : (which == 3) ? Wc2 : Wm;
  #pragma unroll
  for (int j = 0; j < 4; ++j)
    a_s[j][tid] = A[(m0 + j) * ND + tid];
  __syncthreads();
  float acc[4] = {0.f, 0.f, 0.f, 0.f};
  for (int k = 0; k < 256; ++k) {
    const float w = W[k * NH + tid];
    acc[0] += a_s[0][k] * w;
    acc[1] += a_s[1][k] * w;
    acc[2] += a_s[2][k] * w;
    acc[3] += a_s[3][k] * w;
  }
  if (which == 2) {
    #pragma unroll
    for (int j = 0; j < 4; ++j) ws[(m0 + j) * NH + tid] = acc[j];
  } else if (which >= 3) {
    float* O = (float*)((char*)ws + 2097152 + (which - 3) * 1048576);
    #pragma unroll
    for (int j = 0; j < 4; ++j) O[(m0 + j) * NH + tid] = acc[j];
  } else {
    unsigned short* O = (unsigned short*)((char*)ws + 1048576 + which * 524288);
    #pragma unroll
    for (int j = 0; j < 4; ++j) O[(m0 + j) * NH + tid] = f2b(acc[j]);
  }
}

__global__ void __launch_bounds__(256) fused_multiway(
    const float* __restrict__ Hp, const float* __restrict__ Hq,
    const float* __restrict__ Wd, const float* __restrict__ vc,
    const float* __restrict__ vd, const float* __restrict__ vm,
    const float* __restrict__ ws, float* __restrict__ out)
{
  const int p = blockIdx.x, b = blockIdx.y;
  const int tid = threadIdx.x;
  const int wave = tid >> 6, lane = tid & 63;
  const int quad = lane >> 4, c16 = lane & 15;

  __shared__ __align__(16) short Bs[64 * 264];   // [h][k], stride 264 (2-way banks)
  __shared__ __align__(16) float sc4[4 * 256];   // rows: 0=c 1=b 2=d 3=m
  __shared__ __align__(16) float hp_s[256];
  __shared__ __align__(16) float c2_s[256];
  __shared__ __align__(16) float m2_s[256];
  __shared__ __align__(16) float vc_s[256];
  __shared__ __align__(16) float vd_s[256];
  __shared__ __align__(16) float vm_s[256];
  __shared__ __align__(16) float invsum[4];

  const float* X = ws;
  const unsigned short* C1 = (const unsigned short*)((const char*)ws + 1048576);
  const unsigned short* M1 = (const unsigned short*)((const char*)ws + 1572864);
  const float* C2F = (const float*)((const char*)ws + 2097152);
  const float* M2F = (const float*)((const char*)ws + 3145728);
  const unsigned short* Hqb = (const unsigned short*)((const char*)ws + 4194304);

  { // phase 0
    const int r = (b * NL + p) * ND + tid;
    hp_s[tid] = Hp[r];
    c2_s[tid] = C2F[r];
    m2_s[tid] = M2F[r];
    vc_s[tid] = vc[tid];
    vd_s[tid] = vd[tid];
    vm_s[tid] = vm[tid];
  }
  __syncthreads();

  auto do_scores = [&]() {
    const int qsub = lane >> 4;
    const int hb = c16 * 4;
    for (int qg = 0; qg < 16; ++qg) {
      const int q = wave * 64 + qg * 4 + qsub;
      const unsigned short* c1r = C1 + (b * NL + q) * NH;
      const unsigned short* m1r = M1 + (b * NL + q) * NH;
      const float* xr = X + (b * NL + q) * ND;
      float pc = 0.f, pm = 0.f, pb = 0.f;
      #pragma unroll
      for (int hi = 0; hi < 4; ++hi) {
        const int h = hb + hi * 64;
        s16x4 c1v = *(const s16x4*)(c1r + h);
        s16x4 m1v = *(const s16x4*)(m1r + h);
        f32x4 xv  = *(const f32x4*)(xr + h);
        #pragma unroll
        for (int i = 0; i < 4; ++i) {
          pc += vc_s[h + i] * ftanh(b2f((unsigned short)c1v[i]) + c2_s[h + i]);
          pm += vm_s[h + i] * ftanh(b2f((unsigned short)m1v[i]) - m2_s[h + i]);
          pb += hp_s[h + i] * xv[i];
        }
      }
      #pragma unroll
      for (int m = 1; m < 16; m <<= 1) {
        pc += __shfl_xor(pc, m, 64);
        pm += __shfl_xor(pm, m, 64);
        pb += __shfl_xor(pb, m, 64);
      }
      if (c16 == 0) {
        sc4[q]       = pc;
        sc4[256 + q] = pb;
        sc4[768 + q] = pm;
      }
    }
  };

  auto do_dbranch = [&]() {
    const int wq0 = wave * 64;
    const unsigned short* Aq = Hqb + (b * NL + wq0) * ND;
    float sd_reg[4][4];
    #pragma unroll
    for (int mt = 0; mt < 4; ++mt)
      #pragma unroll
      for (int r = 0; r < 4; ++r) sd_reg[mt][r] = 0.f;

    for (int ht = 0; ht < 4; ++ht) {
      const int h0 = ht * 64;
      __syncthreads();   // protect Bs re-staging vs previous ht's reads
      { // stage Bs[h][k] = bf16(Wd[k][h0+h] * hp[k]) for full k; wave w: k in [w*64,w*64+64)
        const int h = lane;
        const int kb = wave * 64;
        for (int i = 0; i < 8; ++i) {
          s16x8 bv;
          #pragma unroll
          for (int j = 0; j < 8; ++j) {
            const int k = kb + i * 8 + j;
            bv[j] = (short)f2b(Wd[k * NH + h0 + h] * hp_s[k]);
          }
          *(s16x8*)(Bs + h * 264 + kb + i * 8) = bv;
        }
      }
      __syncthreads();

      f32x4 acc[4][4];
      #pragma unroll
      for (int mt = 0; mt < 4; ++mt)
        #pragma unroll
        for (int nt = 0; nt < 4; ++nt) acc[mt][nt] = f32x4{0.f, 0.f, 0.f, 0.f};

      #pragma unroll 2
      for (int kt = 0; kt < 8; ++kt) {
        const int k0 = kt * 32;
        s16x8 a8[4], b8[4];
        #pragma unroll
        for (int mt = 0; mt < 4; ++mt)
          a8[mt] = *(const s16x8*)(Aq + (mt * 16 + c16) * ND + k0 + quad * 8);
        #pragma unroll
        for (int nt = 0; nt < 4; ++nt)
          b8[nt] = *(const s16x8*)(Bs + (nt * 16 + c16) * 264 + k0 + quad * 8);
        #pragma unroll
        for (int nt = 0; nt < 4; ++nt)
          #pragma unroll
          for (int mt = 0; mt < 4; ++mt)
            acc[mt][nt] = __builtin_amdgcn_mfma_f32_16x16x32_bf16(
                a8[mt], b8[nt], acc[mt][nt], 0, 0, 0);
      }

      // epilogue: sd[q] += sum_h vd[h]*tanh(Z[q,h]); C/D: col=lane&15, row=quad*4+r
      #pragma unroll
      for (int mt = 0; mt < 4; ++mt) {
        float part[4] = {0.f, 0.f, 0.f, 0.f};
        #pragma unroll
        for (int nt = 0; nt < 4; ++nt) {
          const float vdh = vd_s[h0 + nt * 16 + c16];
          #pragma unroll
          for (int r = 0; r < 4; ++r)
            part[r] += vdh * ftanh(acc[mt][nt][r]);
        }
        #pragma unroll
        for (int r = 0; r < 4; ++r) {
          float v = part[r];
          #pragma unroll
          for (int m = 1; m < 16; m <<= 1) v += __shfl_xor(v, m, 64);
          sd_reg[mt][r] += v;
        }
      }
    }
    if (c16 == 0) {
      #pragma unroll
      for (int mt = 0; mt < 4; ++mt)
        #pragma unroll
        for (int r = 0; r < 4; ++r)
          sc4[512 + wq0 + mt * 16 + quad * 4 + r] = sd_reg[mt][r];
    }
  };

  // parity swap: co-resident blocks overlap VALU phase with MFMA phase
  if (((p ^ b) & 1) == 0) { do_scores(); do_dbranch(); }
  else                    { do_dbranch(); do_scores(); }

  __syncthreads();

  { // softmax; wave w owns branch w (0=c,1=b,2=d,3=m)
    float s0 = sc4[wave * 256 + lane];
    float s1 = sc4[wave * 256 + lane + 64];
    float s2 = sc4[wave * 256 + lane + 128];
    float s3 = sc4[wave * 256 + lane + 192];
    float mx = fmaxf(fmaxf(s0, s1), fmaxf(s2, s3));
    #pragma unroll
    for (int m = 1; m < 64; m <<= 1) mx = fmaxf(mx, __shfl_xor(mx, m, 64));
    float e0 = __builtin_amdgcn_exp2f((s0 - mx) * LOG2E);
    float e1 = __builtin_amdgcn_exp2f((s1 - mx) * LOG2E);
    float e2 = __builtin_amdgcn_exp2f((s2 - mx) * LOG2E);
    float e3 = __builtin_amdgcn_exp2f((s3 - mx) * LOG2E);
    float sm = e0 + e1 + e2 + e3;
    #pragma unroll
    for (int m = 1; m < 64; m <<= 1) sm += __shfl_xor(sm, m, 64);
    sc4[wave * 256 + lane]       = e0;
    sc4[wave * 256 + lane + 64]  = e1;
    sc4[wave * 256 + lane + 128] = e2;
    sc4[wave * 256 + lane + 192] = e3;
    if (lane == 0) invsum[wave] = __builtin_amdgcn_rcpf(sm);
  }
  __syncthreads();

  { // attend: wave w -> output region w, row (b,p); fp32 out
    float a0 = 0.f, a1 = 0.f, a2 = 0.f, a3 = 0.f;
    for (int q = 0; q < 256; ++q) {
      const float a = sc4[wave * 256 + q];
      f32x4 hv = *(const f32x4*)(Hq + (b * NL + q) * ND + lane * 4);
      a0 += a * hv.x; a1 += a * hv.y; a2 += a * hv.z; a3 += a * hv.w;
    }
    const float inv = invsum[wave];
    f32x4 ov;
    ov.x = a0 * inv;
    ov.y = a1 * inv;
    ov.z = a2 * inv;
    ov.w = a3 * inv;
    *(f32x4*)(out + ((wave * NB + b) * NL + p) * ND + lane * 4) = ov;
  }
}

extern "C" void kernel_launch(void* const* d_in, const int* in_sizes, int n_in,
                              void* d_out, int out_size, void* d_ws, size_t ws_size,
                              hipStream_t stream) {
  const float* Hp  = (const float*)d_in[0];
  const float* Hq  = (const float*)d_in[1];
  const float* Wc1 = (const float*)d_in[2];
  const float* Wc2 = (const float*)d_in[3];
  const float* vc  = (const float*)d_in[4];
  const float* Wb  = (const float*)d_in[5];
  const float* Wd  = (const float*)d_in[6];
  const float* vd  = (const float*)d_in[7];
  const float* Wm  = (const float*)d_in[8];
  const float* vm  = (const float*)d_in[9];
  float* ws = (float*)d_ws;
  float* out = (float*)d_out;

  hipLaunchKernelGGL(prep, dim3(256, 6), dim3(256), 0, stream,
                     Hq, Hp, Wc1, Wc2, Wb, Wm, ws);
  hipLaunchKernelGGL(fused_multiway, dim3(256, 4), dim3(256), 0, stream,
                     Hp, Hq, Wd, vc, vd, vm, ws, out);
}

// Round 9
// 221.715 us; speedup vs baseline: 1.7276x; 1.5537x over previous
//
#include <hip/hip_runtime.h>

#define LOG2E 1.4426950408889634f
#define NB 4
#define NL 256
#define ND 256
#define NH 256

typedef __attribute__((ext_vector_type(8))) short s16x8;
typedef __attribute__((ext_vector_type(4))) short s16x4;
typedef __attribute__((ext_vector_type(4))) float f32x4;

static __device__ __forceinline__ float b2f(unsigned short u) {
  return __builtin_bit_cast(float, (unsigned int)u << 16);
}
static __device__ __forceinline__ unsigned short f2b(float f) {
  unsigned int x = __builtin_bit_cast(unsigned int, f);
  return (unsigned short)((x + 0x7fffu + ((x >> 16) & 1u)) >> 16);
}
static __device__ __forceinline__ float ftanh(float x) {
  float e = __builtin_amdgcn_exp2f(x * 2.8853900817779268f);
  return 1.0f - 2.0f * __builtin_amdgcn_rcpf(e + 1.0f);
}

// ws layout (4.5 MB, same total as R8-proven):
//   X    fp32 [0,      1M)  : Hq@Wb
//   C1   bf16 [1M,   1.5M)  : Hq@Wc1
//   M1   bf16 [1.5M,   2M)  : Hq@Wm
//   C2b  bf16 [2M,   2.5M)  : Hp@Wc2
//   M2b  bf16 [2.5M,   3M)  : Hp@Wm
//   Hqb  bf16 [3M,   3.5M)  : bf16(Hq)
//   SD   fp32 [3.5M, 4.5M)  : branch-d raw scores

__global__ void __launch_bounds__(256) prep(
    const float* __restrict__ Hq, const float* __restrict__ Hp,
    const float* __restrict__ Wc1, const float* __restrict__ Wc2,
    const float* __restrict__ Wb, const float* __restrict__ Wm,
    float* __restrict__ ws)
{
  const int m0 = blockIdx.x * 8;
  const int which = blockIdx.y;  // 0=C1 1=M1 2=X 3=C2b 4=M2b 5=Hqb
  const int tid = threadIdx.x;
  if (which == 5) {
    unsigned short* Hqb = (unsigned short*)((char*)ws + 3145728);
    #pragma unroll
    for (int j = 0; j < 8; ++j)
      Hqb[(m0 + j) * ND + tid] = f2b(Hq[(m0 + j) * ND + tid]);
    return;
  }
  __shared__ __align__(16) float a_s[8][256];
  const float* A = (which >= 3) ? Hp : Hq;
  const float* W = (which == 0) ? Wc1 : (which == 1) ? Wm :
                   (which == 2) ? Wb  : (which == 3) ? Wc2 : Wm;
  #pragma unroll
  for (int j = 0; j < 8; ++j)
    a_s[j][tid] = A[(m0 + j) * ND + tid];
  __syncthreads();
  float acc[8] = {0.f, 0.f, 0.f, 0.f, 0.f, 0.f, 0.f, 0.f};
  for (int k = 0; k < 256; ++k) {
    const float w = W[k * NH + tid];
    #pragma unroll
    for (int j = 0; j < 8; ++j) acc[j] += a_s[j][k] * w;
  }
  if (which == 2) {
    #pragma unroll
    for (int j = 0; j < 8; ++j) ws[(m0 + j) * NH + tid] = acc[j];
  } else if (which < 2) {
    unsigned short* O = (unsigned short*)((char*)ws + 1048576 + which * 524288);
    #pragma unroll
    for (int j = 0; j < 8; ++j) O[(m0 + j) * NH + tid] = f2b(acc[j]);
  } else {
    unsigned short* O = (unsigned short*)((char*)ws + 2097152 + (which - 3) * 524288);
    #pragma unroll
    for (int j = 0; j < 8; ++j) O[(m0 + j) * NH + tid] = f2b(acc[j]);
  }
}

// ---- branch d: per (b,p) MFMA GEMM + tanh reduce -> SD
__global__ void __launch_bounds__(256, 4) dkernel(
    const float* __restrict__ Hp, const float* __restrict__ Wd,
    const float* __restrict__ vd, float* __restrict__ ws)
{
  const int p = blockIdx.x, b = blockIdx.y;
  const int tid = threadIdx.x;
  const int wave = tid >> 6, lane = tid & 63;
  const int quad = lane >> 4, c16 = lane & 15;

  __shared__ __align__(16) short Bs[64 * 264];  // [h][k]
  __shared__ __align__(16) float hp_s[256];
  __shared__ __align__(16) float vd_s[256];

  const unsigned short* Hqb = (const unsigned short*)((const char*)ws + 3145728);
  float* SD = (float*)((char*)ws + 3670016);

  hp_s[tid] = Hp[(b * NL + p) * ND + tid];
  vd_s[tid] = vd[tid];
  __syncthreads();

  const int wq0 = wave * 64;
  const unsigned short* Aq = Hqb + (b * NL + wq0) * ND;
  float sd_reg[4][4];
  #pragma unroll
  for (int mt = 0; mt < 4; ++mt)
    #pragma unroll
    for (int r = 0; r < 4; ++r) sd_reg[mt][r] = 0.f;

  for (int ht = 0; ht < 4; ++ht) {
    const int h0 = ht * 64;
    __syncthreads();
    { // stage Bs[h][k] = bf16(Wd[k][h0+h]*hp[k]); wave w: k in [64w,64w+64)
      const int h = lane;
      const int kb = wave * 64;
      for (int i = 0; i < 8; ++i) {
        s16x8 bv;
        #pragma unroll
        for (int j = 0; j < 8; ++j) {
          const int k = kb + i * 8 + j;
          bv[j] = (short)f2b(Wd[k * NH + h0 + h] * hp_s[k]);
        }
        *(s16x8*)(Bs + h * 264 + kb + i * 8) = bv;
      }
    }
    __syncthreads();

    f32x4 acc[4][4];
    #pragma unroll
    for (int mt = 0; mt < 4; ++mt)
      #pragma unroll
      for (int nt = 0; nt < 4; ++nt) acc[mt][nt] = f32x4{0.f, 0.f, 0.f, 0.f};

    #pragma unroll 2
    for (int kt = 0; kt < 8; ++kt) {
      const int k0 = kt * 32;
      s16x8 a8[4];
      #pragma unroll
      for (int mt = 0; mt < 4; ++mt)
        a8[mt] = *(const s16x8*)(Aq + (mt * 16 + c16) * ND + k0 + quad * 8);
      #pragma unroll
      for (int nt = 0; nt < 4; ++nt) {
        s16x8 b8 = *(const s16x8*)(Bs + (nt * 16 + c16) * 264 + k0 + quad * 8);
        #pragma unroll
        for (int mt = 0; mt < 4; ++mt)
          acc[mt][nt] = __builtin_amdgcn_mfma_f32_16x16x32_bf16(
              a8[mt], b8, acc[mt][nt], 0, 0, 0);
      }
    }

    // sd[q] += sum_h vd[h]*tanh(Z[q,h]); C/D: col=lane&15, row=quad*4+r
    #pragma unroll
    for (int mt = 0; mt < 4; ++mt) {
      float part[4] = {0.f, 0.f, 0.f, 0.f};
      #pragma unroll
      for (int nt = 0; nt < 4; ++nt) {
        const float vdh = vd_s[h0 + nt * 16 + c16];
        #pragma unroll
        for (int r = 0; r < 4; ++r)
          part[r] += vdh * ftanh(acc[mt][nt][r]);
      }
      #pragma unroll
      for (int r = 0; r < 4; ++r) {
        float v = part[r];
        #pragma unroll
        for (int m = 1; m < 16; m <<= 1) v += __shfl_xor(v, m, 64);
        sd_reg[mt][r] += v;
      }
    }
  }
  if (c16 == 0) {
    #pragma unroll
    for (int mt = 0; mt < 4; ++mt)
      #pragma unroll
      for (int r = 0; r < 4; ++r)
        SD[(b * NL + p) * NL + wq0 + mt * 16 + quad * 4 + r] = sd_reg[mt][r];
  }
}

// ---- scores c/b/m + softmax(all 4) + attend(all 4)
__global__ void __launch_bounds__(256) fused2(
    const float* __restrict__ Hp, const float* __restrict__ Hq,
    const float* __restrict__ vc, const float* __restrict__ vm,
    const float* __restrict__ ws, float* __restrict__ out)
{
  const int p = blockIdx.x, b = blockIdx.y;
  const int tid = threadIdx.x;
  const int wave = tid >> 6, lane = tid & 63;
  const int c16 = lane & 15;

  __shared__ __align__(16) float sc4[4 * 256];  // rows: 0=c 1=b 2=d 3=m
  __shared__ __align__(16) float red[4][4][256]; // [wave][branch][d]
  __shared__ __align__(16) float hp_s[256];
  __shared__ __align__(16) float c2_s[256];
  __shared__ __align__(16) float m2_s[256];
  __shared__ __align__(16) float vc_s[256];
  __shared__ __align__(16) float vm_s[256];
  __shared__ __align__(16) float invsum[4];

  const float* X = ws;
  const unsigned short* C1  = (const unsigned short*)((const char*)ws + 1048576);
  const unsigned short* M1  = (const unsigned short*)((const char*)ws + 1572864);
  const unsigned short* C2b = (const unsigned short*)((const char*)ws + 2097152);
  const unsigned short* M2b = (const unsigned short*)((const char*)ws + 2621440);
  const float* SD = (const float*)((const char*)ws + 3670016);

  {
    const int r = (b * NL + p) * ND + tid;
    hp_s[tid] = Hp[r];
    c2_s[tid] = b2f(C2b[r]);
    m2_s[tid] = b2f(M2b[r]);
    vc_s[tid] = vc[tid];
    vm_s[tid] = vm[tid];
    sc4[512 + tid] = SD[(b * NL + p) * NL + tid];
  }
  __syncthreads();

  { // scores c, b, m
    const int qsub = lane >> 4;
    const int hb = c16 * 4;
    for (int qg = 0; qg < 16; ++qg) {
      const int q = wave * 64 + qg * 4 + qsub;
      const unsigned short* c1r = C1 + (b * NL + q) * NH;
      const unsigned short* m1r = M1 + (b * NL + q) * NH;
      const float* xr = X + (b * NL + q) * ND;
      float pc = 0.f, pm = 0.f, pb = 0.f;
      #pragma unroll
      for (int hi = 0; hi < 4; ++hi) {
        const int h = hb + hi * 64;
        s16x4 c1v = *(const s16x4*)(c1r + h);
        s16x4 m1v = *(const s16x4*)(m1r + h);
        f32x4 xv  = *(const f32x4*)(xr + h);
        #pragma unroll
        for (int i = 0; i < 4; ++i) {
          pc += vc_s[h + i] * ftanh(b2f((unsigned short)c1v[i]) + c2_s[h + i]);
          pm += vm_s[h + i] * ftanh(b2f((unsigned short)m1v[i]) - m2_s[h + i]);
          pb += hp_s[h + i] * xv[i];
        }
      }
      #pragma unroll
      for (int m = 1; m < 16; m <<= 1) {
        pc += __shfl_xor(pc, m, 64);
        pm += __shfl_xor(pm, m, 64);
        pb += __shfl_xor(pb, m, 64);
      }
      if (c16 == 0) {
        sc4[q]       = pc;
        sc4[256 + q] = pb;
        sc4[768 + q] = pm;
      }
    }
  }
  __syncthreads();

  { // softmax; wave w owns branch w (0=c,1=b,2=d,3=m)
    float s0 = sc4[wave * 256 + lane];
    float s1 = sc4[wave * 256 + lane + 64];
    float s2 = sc4[wave * 256 + lane + 128];
    float s3 = sc4[wave * 256 + lane + 192];
    float mx = fmaxf(fmaxf(s0, s1), fmaxf(s2, s3));
    #pragma unroll
    for (int m = 1; m < 64; m <<= 1) mx = fmaxf(mx, __shfl_xor(mx, m, 64));
    float e0 = __builtin_amdgcn_exp2f((s0 - mx) * LOG2E);
    float e1 = __builtin_amdgcn_exp2f((s1 - mx) * LOG2E);
    float e2 = __builtin_amdgcn_exp2f((s2 - mx) * LOG2E);
    float e3 = __builtin_amdgcn_exp2f((s3 - mx) * LOG2E);
    float sm = e0 + e1 + e2 + e3;
    #pragma unroll
    for (int m = 1; m < 64; m <<= 1) sm += __shfl_xor(sm, m, 64);
    sc4[wave * 256 + lane]       = e0;
    sc4[wave * 256 + lane + 64]  = e1;
    sc4[wave * 256 + lane + 128] = e2;
    sc4[wave * 256 + lane + 192] = e3;
    if (lane == 0) invsum[wave] = __builtin_amdgcn_rcpf(sm);
  }
  __syncthreads();

  { // attend: wave w covers q in [64w,64w+64) for ALL branches; Hq read once
    const int q0 = wave * 64;
    f32x4 pa0 = {0.f,0.f,0.f,0.f}, pa1 = {0.f,0.f,0.f,0.f};
    f32x4 pa2 = {0.f,0.f,0.f,0.f}, pa3 = {0.f,0.f,0.f,0.f};
    for (int qi = 0; qi < 64; ++qi) {
      const int q = q0 + qi;
      const float ac = sc4[q];
      const float ab = sc4[256 + q];
      const float ad = sc4[512 + q];
      const float am = sc4[768 + q];
      f32x4 hv = *(const f32x4*)(Hq + (b * NL + q) * ND + lane * 4);
      pa0 += ac * hv; pa1 += ab * hv; pa2 += ad * hv; pa3 += am * hv;
    }
    *(f32x4*)(&red[wave][0][lane * 4]) = pa0;
    *(f32x4*)(&red[wave][1][lane * 4]) = pa1;
    *(f32x4*)(&red[wave][2][lane * 4]) = pa2;
    *(f32x4*)(&red[wave][3][lane * 4]) = pa3;
  }
  __syncthreads();

  { // cross-wave reduce + normalize + store; thread owns d=tid for 4 branches
    #pragma unroll
    for (int br = 0; br < 4; ++br) {
      float s = red[0][br][tid] + red[1][br][tid] + red[2][br][tid] + red[3][br][tid];
      out[((br * NB + b) * NL + p) * ND + tid] = s * invsum[br];
    }
  }
}

extern "C" void kernel_launch(void* const* d_in, const int* in_sizes, int n_in,
                              void* d_out, int out_size, void* d_ws, size_t ws_size,
                              hipStream_t stream) {
  const float* Hp  = (const float*)d_in[0];
  const float* Hq  = (const float*)d_in[1];
  const float* Wc1 = (const float*)d_in[2];
  const float* Wc2 = (const float*)d_in[3];
  const float* vc  = (const float*)d_in[4];
  const float* Wb  = (const float*)d_in[5];
  const float* Wd  = (const float*)d_in[6];
  const float* vd  = (const float*)d_in[7];
  const float* Wm  = (const float*)d_in[8];
  const float* vm  = (const float*)d_in[9];
  float* ws = (float*)d_ws;
  float* out = (float*)d_out;

  hipLaunchKernelGGL(prep, dim3(128, 6), dim3(256), 0, stream,
                     Hq, Hp, Wc1, Wc2, Wb, Wm, ws);
  hipLaunchKernelGGL(dkernel, dim3(256, 4), dim3(256), 0, stream,
                     Hp, Wd, vd, ws);
  hipLaunchKernelGGL(fused2, dim3(256, 4), dim3(256), 0, stream,
                     Hp, Hq, vc, vm, ws, out);
}